// Round 11
// baseline (220.992 us; speedup 1.0000x reference)
//
#include <hip/hip_runtime.h>

typedef unsigned short u16;
typedef unsigned int u32;
typedef __attribute__((ext_vector_type(8))) short s16x8;   // 8 bf16 (4 VGPRs) MFMA A/B frag
typedef __attribute__((ext_vector_type(4))) short s16x4;   // 4 bf16 (2 VGPRs)
typedef __attribute__((ext_vector_type(4))) float f32x4;   // MFMA C/D frag

#define DIM    1024
#define NHEADS 16
#define HD     64
#define NSEQ   2048
#define QKVN   3072

__device__ __forceinline__ u16 f2bf(float f) {
  u32 u = __float_as_uint(f);
  u += 0x7FFF + ((u >> 16) & 1);   // RNE
  return (u16)(u >> 16);
}

// exp2 via the compiler-visible intrinsic (single v_exp_f32 WITH hazard padding).
__device__ __forceinline__ float vexp2(float x) {
#if __has_builtin(__builtin_amdgcn_exp2f)
  return __builtin_amdgcn_exp2f(x);
#else
  return __expf(x * 0.69314718055994531f);
#endif
}

// async global->LDS, 16B per lane. LDS dst = wave-uniform base + lane*16.
__device__ __forceinline__ void async16(const u16* g, u16* l) {
  __builtin_amdgcn_global_load_lds(
      (const __attribute__((address_space(1))) unsigned int*)g,
      (__attribute__((address_space(3))) unsigned int*)l, 16, 0, 0);
}

// ---------------------------------------------------------------- cast fp32 -> bf16
__global__ void cast_all(const float* __restrict__ x, const float* __restrict__ wq,
                         const float* __restrict__ wp, u16* __restrict__ xo,
                         u16* __restrict__ wqo, u16* __restrict__ wpo) {
  int i = blockIdx.x * 256 + threadIdx.x;        // 2,097,152 threads, 4 floats each
  const float4* src; u16* dst; int off;
  if (i < 1048576)      { src = (const float4*)x;  dst = xo;  off = i; }
  else if (i < 1835008) { src = (const float4*)wq; dst = wqo; off = i - 1048576; }
  else                  { src = (const float4*)wp; dst = wpo; off = i - 1835008; }
  float4 f = src[off];
  ushort4 o;
  o.x = f2bf(f.x); o.y = f2bf(f.y); o.z = f2bf(f.z); o.w = f2bf(f.w);
  ((ushort4*)dst)[off] = o;
}

// ---------------------------------------------------------------- GEMM  C = A * B^T
// EXACT round-4 GEMM structure (2-deep prefetch; 11-run ledger: all micro-
// variants within env+noise floor — structure frozen).
// Round-11 addition: Q-columns (n < 1024) of the qkv output are pre-scaled by
// log2(e)/8 before f2bf — one predicated fp32 multiply in the MFMA-bound
// epilogue, deletes attn's entire Q unpack-scale-repack prologue and one
// rounding step (numerics strictly improve).
template <bool FINAL>
__global__ __launch_bounds__(256, 3) void gemm_bt(
    const u16* __restrict__ A, const u16* __restrict__ Bw, u16* __restrict__ qkv,
    u16* __restrict__ vt, const float* __restrict__ bias, float* __restrict__ outp) {
  constexpr int K = 1024;
  constexpr int BM = FINAL ? 64 : 128;
  constexpr int MT = FINAL ? 64 : 32;
  constexpr int IT = FINAL ? 2 : 4;           // 16-row i-tiles per wave
  constexpr int ACALLS = BM / 16;             // wave-calls to stage A tile (1 KB each)
  constexpr int TCALLS = ACALLS + 8;
  constexpr int PW = TCALLS / 4;              // calls per wave
  const float QS = 0.18033688011112042f;      // log2(e)/8
  const int bm = blockIdx.x % MT;
  const int bn = blockIdx.x / MT;
  const int tid = threadIdx.x;
  const int wave = tid >> 6, lane = tid & 63;
  const int q4 = lane >> 4, l15 = lane & 15;
  const int wm = wave >> 1, wn = wave & 1;
  const int m0 = bm * BM, n0 = bn * 128;

  __shared__ alignas(16) u16 lsA[2][BM * 32];
  __shared__ alignas(16) u16 lsB[2][128 * 32];

  f32x4 acc[IT][4];
#pragma unroll
  for (int i = 0; i < IT; i++)
#pragma unroll
    for (int j = 0; j < 4; j++) acc[i][j] = (f32x4){0.f, 0.f, 0.f, 0.f};

  auto stage = [&](int k0, int buf) {
#pragma unroll
    for (int j = 0; j < PW; ++j) {
      int t = wave * PW + j;
      if (t < ACALLS) {
        int lin = t * 64 + lane;
        int r = lin >> 2, c = lin & 3;         // 4 x 16B chunks per 32-elem row
        async16(A + (size_t)(m0 + r) * K + k0 + c * 8, lsA[buf] + t * 512);
      } else {
        int tb = t - ACALLS;
        int lin = tb * 64 + lane;
        int r = lin >> 2, c = lin & 3;
        async16(Bw + (size_t)(n0 + r) * K + k0 + c * 8, lsB[buf] + tb * 512);
      }
    }
  };

  stage(0, 0);

  for (int k0 = 0; k0 < K; k0 += 32) {
    const int buf = (k0 >> 5) & 1;
    __syncthreads();                           // stage(k0) landed; prev compute done
    if (k0 + 32 < K) stage(k0 + 32, buf ^ 1);  // prefetch next into other buffer
    s16x8 af[IT], bfr[4];
#pragma unroll
    for (int i = 0; i < IT; ++i)
      af[i] = *(const s16x8*)(lsA[buf] + (wm * (IT * 16) + i * 16 + l15) * 32 + q4 * 8);
#pragma unroll
    for (int j = 0; j < 4; ++j)
      bfr[j] = *(const s16x8*)(lsB[buf] + (wn * 64 + j * 16 + l15) * 32 + q4 * 8);
    __builtin_amdgcn_s_setprio(1);
#pragma unroll
    for (int i = 0; i < IT; ++i)
#pragma unroll
      for (int j = 0; j < 4; ++j)
        acc[i][j] = __builtin_amdgcn_mfma_f32_16x16x32_bf16(af[i], bfr[j], acc[i][j], 0, 0, 0);
    __builtin_amdgcn_s_setprio(0);
  }

  // epilogue: C/D layout col=lane&15, row=quad*4+reg
#pragma unroll
  for (int i = 0; i < IT; i++) {
#pragma unroll
    for (int j = 0; j < 4; j++) {
      int n = n0 + wn * 64 + j * 16 + l15;
      int mb = m0 + wm * (IT * 16) + i * 16 + q4 * 4;
      if (FINAL) {
#pragma unroll
        for (int r = 0; r < 4; r++)
          outp[(size_t)(mb + r) * DIM + n] = acc[i][j][r] + bias[n];
      } else if (n < 2048) {
        float sc = (n < 1024) ? QS : 1.0f;     // pre-scale Q columns for attn
#pragma unroll
        for (int r = 0; r < 4; r++)
          qkv[(size_t)(mb + r) * QKVN + n] = f2bf(acc[i][j][r] * sc);
      } else {
        int b = mb >> 11, tok = mb & 2047;
        int h = (n >> 6) & 15, hd = n & 63;
        ushort4 pk;
        pk.x = f2bf(acc[i][j][0]); pk.y = f2bf(acc[i][j][1]);
        pk.z = f2bf(acc[i][j][2]); pk.w = f2bf(acc[i][j][3]);
        *(ushort4*)(vt + ((size_t)((b * NHEADS + h) * HD + hd)) * NSEQ + tok) = pk;
      }
    }
  }
}

// ---------------------------------------------------------------- flash attention
// Round-11 = R10 (best: 47.3us attn, 171.8 total) + two VALU/serial cuts:
// 1) Q arrives PRE-SCALED from gemm1 -> prologue is a raw uint4 reinterpret
//    (deletes ~400 unpack-scale-repack VALU ops/wave).
// 2) SYMMETRIC epilogue: g1 publishes ht{0,1}, g0 publishes ht{2,3} (+both
//    publish sums); g0 finishes cols 0-31, g1 finishes cols 32-63. Per-lane
//    epilogue work halves; no idle waves. Overlay 34,816B < 64KB.
// Kept: x32-permuted PV (R8), matrix-pipe osum + setprio (R10, -3.2us A/B'd).
// Reverted history: (256,4) spills; 64-row Q-tiles; kt=32; 8-wave blocks
// (conflicts 2x); hand vmcnt pipelining (R6).
__global__ __launch_bounds__(256, 2) void attn_kernel(const u16* __restrict__ qkv,
                                                      const u16* __restrict__ vt,
                                                      u16* __restrict__ aout) {
  const int blk = blockIdx.x;            // 512 = 16 qtiles * 32 bh (bh fast)
  const int bh = blk & 31, qt = blk >> 5;
  const int b = bh >> 4, h = bh & 15;
  const int tid = threadIdx.x;
  const int wave = tid >> 6, lane = tid & 63;
  const int g = wave >> 1, wq = wave & 1;      // key-group, q-position
  const int q4 = lane >> 4, l15 = lane & 15;

  __shared__ alignas(16) u16 smem[32768];      // 64 KB, hand-partitioned
  u16* lsKb = smem + g * 2 * 4096;             // this group's two K buffers
  u16* lsVb = smem + 16384 + g * 2 * 4096;     // this group's two V buffers

  // Q frags (B-operand of S^T MFMA) — pre-scaled by log2(e)/8 in gemm1
  s16x8 aq[4][2];
#pragma unroll
  for (int rt = 0; rt < 4; ++rt)
#pragma unroll
    for (int kc = 0; kc < 2; ++kc) {
      int row = b * NSEQ + qt * 128 + wq * 64 + rt * 16 + l15;
      aq[rt][kc] = *(const s16x8*)(qkv + (size_t)row * QKVN + h * HD + kc * 32 + q4 * 8);
    }

  f32x4 o[4][4];
  f32x4 osum[4];                                   // rowsum(P): row = q4*4+r, dup over l15
  const s16x8 vones8 = {(short)0x3F80, (short)0x3F80, (short)0x3F80, (short)0x3F80,
                        (short)0x3F80, (short)0x3F80, (short)0x3F80, (short)0x3F80};
#pragma unroll
  for (int rt = 0; rt < 4; ++rt) {
    osum[rt] = (f32x4){0.f, 0.f, 0.f, 0.f};
#pragma unroll
    for (int ht = 0; ht < 4; ++ht) o[rt][ht] = (f32x4){0.f, 0.f, 0.f, 0.f};
  }

  // stage tile ktl of this group's key-half into buffer buf (8 K + 8 V calls / 2 waves)
  auto stage = [&](int ktl, int buf) {
#pragma unroll
    for (int j = 0; j < 4; ++j) {
      int t = wq * 4 + j;                          // 0..7
      int lin = t * 64 + lane;
      int r = lin >> 3, c = (lin & 7) ^ (r & 7);
      int key = g * 1024 + ktl * 64;
      async16(qkv + (size_t)(b * NSEQ + key + r) * QKVN + DIM + h * HD + c * 8,
              lsKb + buf * 4096 + t * 512);
      async16(vt + (size_t)(bh * HD + r) * NSEQ + key + c * 8,
              lsVb + buf * 4096 + t * 512);
    }
  };

  stage(0, 0);

  for (int kt = 0; kt < 16; ++kt) {
    const int buf = kt & 1;
    __syncthreads();                               // stage(kt) complete; prev compute done
    if (kt + 1 < 16) stage(kt + 1, buf ^ 1);       // async into other buffer
    const u16* lsK = lsKb + buf * 4096;
    const u16* lsV = lsVb + buf * 4096;

    // hoisted fragment loads (shared by all 4 rt chains)
    s16x8 kf[2][4];                                // [kc][ct]: A-frag K[key][hd]
#pragma unroll
    for (int kc = 0; kc < 2; ++kc)
#pragma unroll
      for (int ct = 0; ct < 4; ++ct) {
        int r = ct * 16 + l15;
        int c = (kc * 4 + q4) ^ (r & 7);
        kf[kc][ct] = *(const s16x8*)(lsK + r * 64 + c * 8);
      }
    // V B-frags in PERMUTED slot order matching pa8 (R8 layout):
    // slot j<4 = keys 32c+4q4+j, slot j>=4 = keys 32c+16+4q4+j-4.
    s16x8 vf8[2][4];                               // [c(32-key chunk)][ht]
#pragma unroll
    for (int c = 0; c < 2; ++c)
#pragma unroll
      for (int ht = 0; ht < 4; ++ht) {
        int row = ht * 16 + l15;                   // hd row in lsV
        int ch0 = c * 4 + (q4 >> 1);               // 16B chunk of keys 32c+4q4..
        int ch1 = ch0 + 2;                         // 16B chunk of keys 32c+16+4q4..
        union { s16x4 hh[2]; s16x8 v; } u;
        u.hh[0] = *(const s16x4*)(lsV + row * 64 + (ch0 ^ (row & 7)) * 8 + (q4 & 1) * 4);
        u.hh[1] = *(const s16x4*)(lsV + row * 64 + (ch1 ^ (row & 7)) * 8 + (q4 & 1) * 4);
        vf8[c][ht] = u.v;
      }

#pragma unroll
    for (int rt = 0; rt < 4; ++rt) {
      // S^T = K * Q^T : per ct, 16 keys x 16 qrows
      f32x4 st[4];
#pragma unroll
      for (int ct = 0; ct < 4; ++ct) st[ct] = (f32x4){0.f, 0.f, 0.f, 0.f};
      __builtin_amdgcn_s_setprio(1);
#pragma unroll
      for (int kc = 0; kc < 2; ++kc)
#pragma unroll
        for (int ct = 0; ct < 4; ++ct)
          st[ct] = __builtin_amdgcn_mfma_f32_16x16x32_bf16(kf[kc][ct], aq[rt][kc], st[ct], 0, 0, 0);
      __builtin_amdgcn_s_setprio(0);

      // P = exp2(S^T), truncated to bf16 in-register, packed directly as the
      // x32 A-frag (w[0..1] = ct=2c, w[2..3] = ct=2c+1)
      s16x8 pa8[2];
#pragma unroll
      for (int c = 0; c < 2; ++c) {
        union { u32 w[4]; s16x8 v; } pk;
#pragma unroll
        for (int h2 = 0; h2 < 2; ++h2) {
          int ct = c * 2 + h2;
          u32 u0 = __float_as_uint(vexp2(st[ct][0]));
          u32 u1 = __float_as_uint(vexp2(st[ct][1]));
          u32 u2 = __float_as_uint(vexp2(st[ct][2]));
          u32 u3 = __float_as_uint(vexp2(st[ct][3]));
          pk.w[h2 * 2 + 0] = (u0 >> 16) | (u1 & 0xffff0000u);
          pk.w[h2 * 2 + 1] = (u2 >> 16) | (u3 & 0xffff0000u);
        }
        pa8[c] = pk.v;
      }

      // O += P * V (16x16x32); rowsum(P) on the matrix pipe (normalizer ==
      // exact MFMA input: same truncated bf16 addends, fp32 accumulation)
      __builtin_amdgcn_s_setprio(1);
#pragma unroll
      for (int c = 0; c < 2; ++c) {
        osum[rt] = __builtin_amdgcn_mfma_f32_16x16x32_bf16(pa8[c], vones8, osum[rt], 0, 0, 0);
#pragma unroll
        for (int ht = 0; ht < 4; ++ht)
          o[rt][ht] = __builtin_amdgcn_mfma_f32_16x16x32_bf16(pa8[c], vf8[c][ht], o[rt][ht], 0, 0, 0);
      }
      __builtin_amdgcn_s_setprio(0);
    }
  }

  // ---- symmetric combine: each group publishes the half the OTHER finishes.
  // Overlay: lsOa (g1's ht{0,1}) 32x132, lsOb (g0's ht{2,3}) 32x132,
  // lsS0 (g0 sums) 128, lsS1 (g1 sums) 128  -> 34,816 B < 64 KB.
  float* lsOa = (float*)smem;
  float* lsOb = lsOa + 32 * 132;
  float* lsS0 = lsOa + 64 * 132;
  float* lsS1 = lsS0 + 128;

  __syncthreads();                                 // all staging reads done; overlay LDS
  {
    float* dst = (g == 1) ? lsOa : lsOb;           // g1 publishes ht01, g0 publishes ht23
    int hb = (g == 1) ? 0 : 2;
    float* ds = (g == 0) ? lsS0 : lsS1;
#pragma unroll
    for (int rt = 0; rt < 4; ++rt) {
#pragma unroll
      for (int hl = 0; hl < 2; ++hl) {
        int ht = hb + hl;
        int addr = (hl * 16 + l15) * 132 + wq * 64 + rt * 16 + q4 * 4;
        *(float4*)(dst + addr) = (float4){o[rt][ht][0], o[rt][ht][1], o[rt][ht][2], o[rt][ht][3]};
      }
      if (l15 == 0) {
#pragma unroll
        for (int r = 0; r < 4; ++r)
          ds[wq * 64 + rt * 16 + q4 * 4 + r] = osum[rt][r];
      }
    }
  }
  __syncthreads();
  {
    int hb = (g == 0) ? 0 : 2;                     // g0 finishes ht01, g1 finishes ht23
    const float* src = (g == 0) ? lsOa : lsOb;
    const float* po = (g == 0) ? lsS1 : lsS0;      // partner's sums
#pragma unroll
    for (int rt = 0; rt < 4; ++rt) {
      float4 s2 = *(const float4*)(po + wq * 64 + rt * 16 + q4 * 4);
      float inv[4];
      inv[0] = 1.0f / (osum[rt][0] + s2.x);
      inv[1] = 1.0f / (osum[rt][1] + s2.y);
      inv[2] = 1.0f / (osum[rt][2] + s2.z);
      inv[3] = 1.0f / (osum[rt][3] + s2.w);
#pragma unroll
      for (int hl = 0; hl < 2; ++hl) {
        int ht = hb + hl;
        float4 o2 = *(const float4*)(src + (hl * 16 + l15) * 132 + wq * 64 + rt * 16 + q4 * 4);
        float v[4] = {o[rt][ht][0] + o2.x, o[rt][ht][1] + o2.y,
                      o[rt][ht][2] + o2.z, o[rt][ht][3] + o2.w};
#pragma unroll
        for (int r = 0; r < 4; ++r) {
          int n = qt * 128 + wq * 64 + rt * 16 + q4 * 4 + r;
          int col = h * HD + ht * 16 + l15;
          aout[(size_t)(b * NSEQ + n) * DIM + col] = f2bf(v[r] * inv[r]);
        }
      }
    }
  }
}

// ---------------------------------------------------------------- launch
extern "C" void kernel_launch(void* const* d_in, const int* in_sizes, int n_in,
                              void* d_out, int out_size, void* d_ws, size_t ws_size,
                              hipStream_t stream) {
  const float* x     = (const float*)d_in[0];
  const float* w_qkv = (const float*)d_in[1];
  const float* w_prj = (const float*)d_in[2];
  const float* b_prj = (const float*)d_in[3];
  float* out = (float*)d_out;

  char* ws = (char*)d_ws;
  u16* x_bf    = (u16*)(ws);                          // 8 MB
  u16* wqkv_bf = (u16*)(ws + (size_t)(8u << 20));     // 6 MB
  u16* wprj_bf = (u16*)(ws + (size_t)(14u << 20));    // 2 MB
  u16* qkv     = (u16*)(ws + (size_t)(16u << 20));    // 24 MB (Q,K used; V slot unused)
  u16* vt      = (u16*)(ws + (size_t)(40u << 20));    // 8 MB
  u16* aout    = (u16*)(ws + (size_t)(48u << 20));    // 8 MB   total 56 MB

  cast_all<<<8192, 256, 0, stream>>>(x, w_qkv, w_prj, x_bf, wqkv_bf, wprj_bf);
  gemm_bt<false><<<32 * 24, 256, 0, stream>>>(x_bf, wqkv_bf, qkv, vt, nullptr, nullptr);
  attn_kernel<<<512, 256, 0, stream>>>(qkv, vt, aout);
  gemm_bt<true><<<64 * 8, 256, 0, stream>>>(aout, wprj_bf, nullptr, nullptr, b_prj, out);
}

// Round 12
// 175.646 us; speedup vs baseline: 1.2582x; 1.2582x over previous
//
#include <hip/hip_runtime.h>

typedef unsigned short u16;
typedef unsigned int u32;
typedef __attribute__((ext_vector_type(8))) short s16x8;   // 8 bf16 (4 VGPRs) MFMA A/B frag
typedef __attribute__((ext_vector_type(4))) short s16x4;   // 4 bf16 (2 VGPRs)
typedef __attribute__((ext_vector_type(4))) float f32x4;   // MFMA C/D frag

#define DIM    1024
#define NHEADS 16
#define HD     64
#define NSEQ   2048
#define QKVN   3072

__device__ __forceinline__ u16 f2bf(float f) {
  u32 u = __float_as_uint(f);
  u += 0x7FFF + ((u >> 16) & 1);   // RNE
  return (u16)(u >> 16);
}

// exp2 via the compiler-visible intrinsic (single v_exp_f32 WITH hazard padding).
__device__ __forceinline__ float vexp2(float x) {
#if __has_builtin(__builtin_amdgcn_exp2f)
  return __builtin_amdgcn_exp2f(x);
#else
  return __expf(x * 0.69314718055994531f);
#endif
}

// async global->LDS, 16B per lane. LDS dst = wave-uniform base + lane*16.
__device__ __forceinline__ void async16(const u16* g, u16* l) {
  __builtin_amdgcn_global_load_lds(
      (const __attribute__((address_space(1))) unsigned int*)g,
      (__attribute__((address_space(3))) unsigned int*)l, 16, 0, 0);
}

// ---------------------------------------------------------------- cast fp32 -> bf16
__global__ void cast_all(const float* __restrict__ x, const float* __restrict__ wq,
                         const float* __restrict__ wp, u16* __restrict__ xo,
                         u16* __restrict__ wqo, u16* __restrict__ wpo) {
  int i = blockIdx.x * 256 + threadIdx.x;        // 2,097,152 threads, 4 floats each
  const float4* src; u16* dst; int off;
  if (i < 1048576)      { src = (const float4*)x;  dst = xo;  off = i; }
  else if (i < 1835008) { src = (const float4*)wq; dst = wqo; off = i - 1048576; }
  else                  { src = (const float4*)wp; dst = wpo; off = i - 1835008; }
  float4 f = src[off];
  ushort4 o;
  o.x = f2bf(f.x); o.y = f2bf(f.y); o.z = f2bf(f.z); o.w = f2bf(f.w);
  ((ushort4*)dst)[off] = o;
}

// ---------------------------------------------------------------- GEMM  C = A * B^T
// EXACT round-4 GEMM structure (2-deep prefetch; ledger: all micro-variants
// within env+noise floor — structure frozen).
// Q-columns (n < 1024) pre-scaled by log2(e)/8 before f2bf (R11): one
// predicated fp32 multiply in the MFMA-bound epilogue; deletes attn's Q
// unpack-scale-repack prologue and one rounding step.
template <bool FINAL>
__global__ __launch_bounds__(256, 3) void gemm_bt(
    const u16* __restrict__ A, const u16* __restrict__ Bw, u16* __restrict__ qkv,
    u16* __restrict__ vt, const float* __restrict__ bias, float* __restrict__ outp) {
  constexpr int K = 1024;
  constexpr int BM = FINAL ? 64 : 128;
  constexpr int MT = FINAL ? 64 : 32;
  constexpr int IT = FINAL ? 2 : 4;           // 16-row i-tiles per wave
  constexpr int ACALLS = BM / 16;             // wave-calls to stage A tile (1 KB each)
  constexpr int TCALLS = ACALLS + 8;
  constexpr int PW = TCALLS / 4;              // calls per wave
  const float QS = 0.18033688011112042f;      // log2(e)/8
  const int bm = blockIdx.x % MT;
  const int bn = blockIdx.x / MT;
  const int tid = threadIdx.x;
  const int wave = tid >> 6, lane = tid & 63;
  const int q4 = lane >> 4, l15 = lane & 15;
  const int wm = wave >> 1, wn = wave & 1;
  const int m0 = bm * BM, n0 = bn * 128;

  __shared__ alignas(16) u16 lsA[2][BM * 32];
  __shared__ alignas(16) u16 lsB[2][128 * 32];

  f32x4 acc[IT][4];
#pragma unroll
  for (int i = 0; i < IT; i++)
#pragma unroll
    for (int j = 0; j < 4; j++) acc[i][j] = (f32x4){0.f, 0.f, 0.f, 0.f};

  auto stage = [&](int k0, int buf) {
#pragma unroll
    for (int j = 0; j < PW; ++j) {
      int t = wave * PW + j;
      if (t < ACALLS) {
        int lin = t * 64 + lane;
        int r = lin >> 2, c = lin & 3;         // 4 x 16B chunks per 32-elem row
        async16(A + (size_t)(m0 + r) * K + k0 + c * 8, lsA[buf] + t * 512);
      } else {
        int tb = t - ACALLS;
        int lin = tb * 64 + lane;
        int r = lin >> 2, c = lin & 3;
        async16(Bw + (size_t)(n0 + r) * K + k0 + c * 8, lsB[buf] + tb * 512);
      }
    }
  };

  stage(0, 0);

  for (int k0 = 0; k0 < K; k0 += 32) {
    const int buf = (k0 >> 5) & 1;
    __syncthreads();                           // stage(k0) landed; prev compute done
    if (k0 + 32 < K) stage(k0 + 32, buf ^ 1);  // prefetch next into other buffer
    s16x8 af[IT], bfr[4];
#pragma unroll
    for (int i = 0; i < IT; ++i)
      af[i] = *(const s16x8*)(lsA[buf] + (wm * (IT * 16) + i * 16 + l15) * 32 + q4 * 8);
#pragma unroll
    for (int j = 0; j < 4; ++j)
      bfr[j] = *(const s16x8*)(lsB[buf] + (wn * 64 + j * 16 + l15) * 32 + q4 * 8);
    __builtin_amdgcn_s_setprio(1);
#pragma unroll
    for (int i = 0; i < IT; ++i)
#pragma unroll
      for (int j = 0; j < 4; ++j)
        acc[i][j] = __builtin_amdgcn_mfma_f32_16x16x32_bf16(af[i], bfr[j], acc[i][j], 0, 0, 0);
    __builtin_amdgcn_s_setprio(0);
  }

  // epilogue: C/D layout col=lane&15, row=quad*4+reg
#pragma unroll
  for (int i = 0; i < IT; i++) {
#pragma unroll
    for (int j = 0; j < 4; j++) {
      int n = n0 + wn * 64 + j * 16 + l15;
      int mb = m0 + wm * (IT * 16) + i * 16 + q4 * 4;
      if (FINAL) {
#pragma unroll
        for (int r = 0; r < 4; r++)
          outp[(size_t)(mb + r) * DIM + n] = acc[i][j][r] + bias[n];
      } else if (n < 2048) {
        float sc = (n < 1024) ? QS : 1.0f;     // pre-scale Q columns for attn
#pragma unroll
        for (int r = 0; r < 4; r++)
          qkv[(size_t)(mb + r) * QKVN + n] = f2bf(acc[i][j][r] * sc);
      } else {
        int b = mb >> 11, tok = mb & 2047;
        int h = (n >> 6) & 15, hd = n & 63;
        ushort4 pk;
        pk.x = f2bf(acc[i][j][0]); pk.y = f2bf(acc[i][j][1]);
        pk.z = f2bf(acc[i][j][2]); pk.w = f2bf(acc[i][j][3]);
        *(ushort4*)(vt + ((size_t)((b * NHEADS + h) * HD + hd)) * NSEQ + tok) = pk;
      }
    }
  }
}

// ---------------------------------------------------------------- flash attention
// Round-12 = R11 mechanisms with the RULE-#20 BUG FIXED. R11's symmetric
// epilogue indexed o[rt][hb+hl] with RUNTIME hb -> the whole o[4][4]
// accumulator (256 B/lane) was demoted to SCRATCH: WRITE_SIZE 8.2MB -> 554MB,
// attn 47 -> 89us (every PV MFMA round-tripped local memory). Fix: g is
// wave-uniform, so publish/finish are explicit uniform branches with LITERAL
// o[rt][0..3] indices — no runtime indexing into ext_vector arrays, ever.
// Kept: pre-scaled-Q raw prologue (R11), symmetric epilogue split (R11),
// x32-permuted PV (R8), matrix-pipe osum + setprio (R10; 50.5->47.3 A/B'd).
// Reverted history: (256,4) spills; 64-row Q-tiles; kt=32; 8-wave blocks
// (conflicts 2x); hand vmcnt pipelining (R6).
__global__ __launch_bounds__(256, 2) void attn_kernel(const u16* __restrict__ qkv,
                                                      const u16* __restrict__ vt,
                                                      u16* __restrict__ aout) {
  const int blk = blockIdx.x;            // 512 = 16 qtiles * 32 bh (bh fast)
  const int bh = blk & 31, qt = blk >> 5;
  const int b = bh >> 4, h = bh & 15;
  const int tid = threadIdx.x;
  const int wave = tid >> 6, lane = tid & 63;
  const int g = wave >> 1, wq = wave & 1;      // key-group, q-position
  const int q4 = lane >> 4, l15 = lane & 15;

  __shared__ alignas(16) u16 smem[32768];      // 64 KB, hand-partitioned
  u16* lsKb = smem + g * 2 * 4096;             // this group's two K buffers
  u16* lsVb = smem + 16384 + g * 2 * 4096;     // this group's two V buffers

  // Q frags (B-operand of S^T MFMA) — pre-scaled by log2(e)/8 in gemm1
  s16x8 aq[4][2];
#pragma unroll
  for (int rt = 0; rt < 4; ++rt)
#pragma unroll
    for (int kc = 0; kc < 2; ++kc) {
      int row = b * NSEQ + qt * 128 + wq * 64 + rt * 16 + l15;
      aq[rt][kc] = *(const s16x8*)(qkv + (size_t)row * QKVN + h * HD + kc * 32 + q4 * 8);
    }

  f32x4 o[4][4];
  f32x4 osum[4];                                   // rowsum(P): row = q4*4+r, dup over l15
  const s16x8 vones8 = {(short)0x3F80, (short)0x3F80, (short)0x3F80, (short)0x3F80,
                        (short)0x3F80, (short)0x3F80, (short)0x3F80, (short)0x3F80};
#pragma unroll
  for (int rt = 0; rt < 4; ++rt) {
    osum[rt] = (f32x4){0.f, 0.f, 0.f, 0.f};
#pragma unroll
    for (int ht = 0; ht < 4; ++ht) o[rt][ht] = (f32x4){0.f, 0.f, 0.f, 0.f};
  }

  // stage tile ktl of this group's key-half into buffer buf (8 K + 8 V calls / 2 waves)
  auto stage = [&](int ktl, int buf) {
#pragma unroll
    for (int j = 0; j < 4; ++j) {
      int t = wq * 4 + j;                          // 0..7
      int lin = t * 64 + lane;
      int r = lin >> 3, c = (lin & 7) ^ (r & 7);
      int key = g * 1024 + ktl * 64;
      async16(qkv + (size_t)(b * NSEQ + key + r) * QKVN + DIM + h * HD + c * 8,
              lsKb + buf * 4096 + t * 512);
      async16(vt + (size_t)(bh * HD + r) * NSEQ + key + c * 8,
              lsVb + buf * 4096 + t * 512);
    }
  };

  stage(0, 0);

  for (int kt = 0; kt < 16; ++kt) {
    const int buf = kt & 1;
    __syncthreads();                               // stage(kt) complete; prev compute done
    if (kt + 1 < 16) stage(kt + 1, buf ^ 1);       // async into other buffer
    const u16* lsK = lsKb + buf * 4096;
    const u16* lsV = lsVb + buf * 4096;

    // hoisted fragment loads (shared by all 4 rt chains)
    s16x8 kf[2][4];                                // [kc][ct]: A-frag K[key][hd]
#pragma unroll
    for (int kc = 0; kc < 2; ++kc)
#pragma unroll
      for (int ct = 0; ct < 4; ++ct) {
        int r = ct * 16 + l15;
        int c = (kc * 4 + q4) ^ (r & 7);
        kf[kc][ct] = *(const s16x8*)(lsK + r * 64 + c * 8);
      }
    // V B-frags in PERMUTED slot order matching pa8 (R8 layout):
    // slot j<4 = keys 32c+4q4+j, slot j>=4 = keys 32c+16+4q4+j-4.
    s16x8 vf8[2][4];                               // [c(32-key chunk)][ht]
#pragma unroll
    for (int c = 0; c < 2; ++c)
#pragma unroll
      for (int ht = 0; ht < 4; ++ht) {
        int row = ht * 16 + l15;                   // hd row in lsV
        int ch0 = c * 4 + (q4 >> 1);               // 16B chunk of keys 32c+4q4..
        int ch1 = ch0 + 2;                         // 16B chunk of keys 32c+16+4q4..
        union { s16x4 hh[2]; s16x8 v; } u;
        u.hh[0] = *(const s16x4*)(lsV + row * 64 + (ch0 ^ (row & 7)) * 8 + (q4 & 1) * 4);
        u.hh[1] = *(const s16x4*)(lsV + row * 64 + (ch1 ^ (row & 7)) * 8 + (q4 & 1) * 4);
        vf8[c][ht] = u.v;
      }

#pragma unroll
    for (int rt = 0; rt < 4; ++rt) {
      // S^T = K * Q^T : per ct, 16 keys x 16 qrows
      f32x4 st[4];
#pragma unroll
      for (int ct = 0; ct < 4; ++ct) st[ct] = (f32x4){0.f, 0.f, 0.f, 0.f};
      __builtin_amdgcn_s_setprio(1);
#pragma unroll
      for (int kc = 0; kc < 2; ++kc)
#pragma unroll
        for (int ct = 0; ct < 4; ++ct)
          st[ct] = __builtin_amdgcn_mfma_f32_16x16x32_bf16(kf[kc][ct], aq[rt][kc], st[ct], 0, 0, 0);
      __builtin_amdgcn_s_setprio(0);

      // P = exp2(S^T), truncated to bf16 in-register, packed directly as the
      // x32 A-frag (w[0..1] = ct=2c, w[2..3] = ct=2c+1)
      s16x8 pa8[2];
#pragma unroll
      for (int c = 0; c < 2; ++c) {
        union { u32 w[4]; s16x8 v; } pk;
#pragma unroll
        for (int h2 = 0; h2 < 2; ++h2) {
          int ct = c * 2 + h2;
          u32 u0 = __float_as_uint(vexp2(st[ct][0]));
          u32 u1 = __float_as_uint(vexp2(st[ct][1]));
          u32 u2 = __float_as_uint(vexp2(st[ct][2]));
          u32 u3 = __float_as_uint(vexp2(st[ct][3]));
          pk.w[h2 * 2 + 0] = (u0 >> 16) | (u1 & 0xffff0000u);
          pk.w[h2 * 2 + 1] = (u2 >> 16) | (u3 & 0xffff0000u);
        }
        pa8[c] = pk.v;
      }

      // O += P * V (16x16x32); rowsum(P) on the matrix pipe (normalizer ==
      // exact MFMA input: same truncated bf16 addends, fp32 accumulation)
      __builtin_amdgcn_s_setprio(1);
#pragma unroll
      for (int c = 0; c < 2; ++c) {
        osum[rt] = __builtin_amdgcn_mfma_f32_16x16x32_bf16(pa8[c], vones8, osum[rt], 0, 0, 0);
#pragma unroll
        for (int ht = 0; ht < 4; ++ht)
          o[rt][ht] = __builtin_amdgcn_mfma_f32_16x16x32_bf16(pa8[c], vf8[c][ht], o[rt][ht], 0, 0, 0);
      }
      __builtin_amdgcn_s_setprio(0);
    }
  }

  // ---- symmetric combine, uniform branches, LITERAL o indices only.
  // Overlay: lsOa (g1's ht{0,1}) 32x132, lsOb (g0's ht{2,3}) 32x132,
  // lsS0 (g0 sums) 128, lsS1 (g1 sums) 128  -> 34,816 B < 64 KB.
  float* lsOa = (float*)smem;
  float* lsOb = lsOa + 32 * 132;
  float* lsS0 = lsOa + 64 * 132;
  float* lsS1 = lsS0 + 128;

  __syncthreads();                                 // all staging reads done; overlay LDS
  if (g == 1) {                                    // publish ht 0,1 + sums
#pragma unroll
    for (int rt = 0; rt < 4; ++rt) {
      int a0 = l15 * 132 + wq * 64 + rt * 16 + q4 * 4;
      *(float4*)(lsOa + a0)            = (float4){o[rt][0][0], o[rt][0][1], o[rt][0][2], o[rt][0][3]};
      *(float4*)(lsOa + a0 + 16 * 132) = (float4){o[rt][1][0], o[rt][1][1], o[rt][1][2], o[rt][1][3]};
      if (l15 == 0) {
#pragma unroll
        for (int r = 0; r < 4; ++r)
          lsS1[wq * 64 + rt * 16 + q4 * 4 + r] = osum[rt][r];
      }
    }
  } else {                                         // publish ht 2,3 + sums
#pragma unroll
    for (int rt = 0; rt < 4; ++rt) {
      int a0 = l15 * 132 + wq * 64 + rt * 16 + q4 * 4;
      *(float4*)(lsOb + a0)            = (float4){o[rt][2][0], o[rt][2][1], o[rt][2][2], o[rt][2][3]};
      *(float4*)(lsOb + a0 + 16 * 132) = (float4){o[rt][3][0], o[rt][3][1], o[rt][3][2], o[rt][3][3]};
      if (l15 == 0) {
#pragma unroll
        for (int r = 0; r < 4; ++r)
          lsS0[wq * 64 + rt * 16 + q4 * 4 + r] = osum[rt][r];
      }
    }
  }
  __syncthreads();
  if (g == 0) {                                    // finish ht 0,1 (cols 0..31)
#pragma unroll
    for (int rt = 0; rt < 4; ++rt) {
      float4 s2 = *(const float4*)(lsS1 + wq * 64 + rt * 16 + q4 * 4);
      float inv[4];
      inv[0] = 1.0f / (osum[rt][0] + s2.x);
      inv[1] = 1.0f / (osum[rt][1] + s2.y);
      inv[2] = 1.0f / (osum[rt][2] + s2.z);
      inv[3] = 1.0f / (osum[rt][3] + s2.w);
      int a0 = l15 * 132 + wq * 64 + rt * 16 + q4 * 4;
      float4 p0 = *(const float4*)(lsOa + a0);
      float4 p1 = *(const float4*)(lsOa + a0 + 16 * 132);
      float v0[4] = {o[rt][0][0] + p0.x, o[rt][0][1] + p0.y, o[rt][0][2] + p0.z, o[rt][0][3] + p0.w};
      float v1[4] = {o[rt][1][0] + p1.x, o[rt][1][1] + p1.y, o[rt][1][2] + p1.z, o[rt][1][3] + p1.w};
#pragma unroll
      for (int r = 0; r < 4; ++r) {
        int n = qt * 128 + wq * 64 + rt * 16 + q4 * 4 + r;
        size_t base = (size_t)(b * NSEQ + n) * DIM + h * HD;
        aout[base + 0  + l15] = f2bf(v0[r] * inv[r]);
        aout[base + 16 + l15] = f2bf(v1[r] * inv[r]);
      }
    }
  } else {                                         // finish ht 2,3 (cols 32..63)
#pragma unroll
    for (int rt = 0; rt < 4; ++rt) {
      float4 s2 = *(const float4*)(lsS0 + wq * 64 + rt * 16 + q4 * 4);
      float inv[4];
      inv[0] = 1.0f / (osum[rt][0] + s2.x);
      inv[1] = 1.0f / (osum[rt][1] + s2.y);
      inv[2] = 1.0f / (osum[rt][2] + s2.z);
      inv[3] = 1.0f / (osum[rt][3] + s2.w);
      int a0 = l15 * 132 + wq * 64 + rt * 16 + q4 * 4;
      float4 p2 = *(const float4*)(lsOb + a0);
      float4 p3 = *(const float4*)(lsOb + a0 + 16 * 132);
      float v2[4] = {o[rt][2][0] + p2.x, o[rt][2][1] + p2.y, o[rt][2][2] + p2.z, o[rt][2][3] + p2.w};
      float v3[4] = {o[rt][3][0] + p3.x, o[rt][3][1] + p3.y, o[rt][3][2] + p3.z, o[rt][3][3] + p3.w};
#pragma unroll
      for (int r = 0; r < 4; ++r) {
        int n = qt * 128 + wq * 64 + rt * 16 + q4 * 4 + r;
        size_t base = (size_t)(b * NSEQ + n) * DIM + h * HD;
        aout[base + 32 + l15] = f2bf(v2[r] * inv[r]);
        aout[base + 48 + l15] = f2bf(v3[r] * inv[r]);
      }
    }
  }
}

// ---------------------------------------------------------------- launch
extern "C" void kernel_launch(void* const* d_in, const int* in_sizes, int n_in,
                              void* d_out, int out_size, void* d_ws, size_t ws_size,
                              hipStream_t stream) {
  const float* x     = (const float*)d_in[0];
  const float* w_qkv = (const float*)d_in[1];
  const float* w_prj = (const float*)d_in[2];
  const float* b_prj = (const float*)d_in[3];
  float* out = (float*)d_out;

  char* ws = (char*)d_ws;
  u16* x_bf    = (u16*)(ws);                          // 8 MB
  u16* wqkv_bf = (u16*)(ws + (size_t)(8u << 20));     // 6 MB
  u16* wprj_bf = (u16*)(ws + (size_t)(14u << 20));    // 2 MB
  u16* qkv     = (u16*)(ws + (size_t)(16u << 20));    // 24 MB (Q,K used; V slot unused)
  u16* vt      = (u16*)(ws + (size_t)(40u << 20));    // 8 MB
  u16* aout    = (u16*)(ws + (size_t)(48u << 20));    // 8 MB   total 56 MB

  cast_all<<<8192, 256, 0, stream>>>(x, w_qkv, w_prj, x_bf, wqkv_bf, wprj_bf);
  gemm_bt<false><<<32 * 24, 256, 0, stream>>>(x_bf, wqkv_bf, qkv, vt, nullptr, nullptr);
  attn_kernel<<<512, 256, 0, stream>>>(qkv, vt, aout);
  gemm_bt<true><<<64 * 8, 256, 0, stream>>>(aout, wprj_bf, nullptr, nullptr, b_prj, out);
}

// Round 13
// 168.019 us; speedup vs baseline: 1.3153x; 1.0454x over previous
//
#include <hip/hip_runtime.h>

typedef unsigned short u16;
typedef unsigned int u32;
typedef __attribute__((ext_vector_type(8))) short s16x8;   // 8 bf16 (4 VGPRs) MFMA A/B frag
typedef __attribute__((ext_vector_type(4))) short s16x4;   // 4 bf16 (2 VGPRs)
typedef __attribute__((ext_vector_type(4))) float f32x4;   // MFMA C/D frag

#define DIM    1024
#define NHEADS 16
#define HD     64
#define NSEQ   2048
#define QKVN   3072

__device__ __forceinline__ u16 f2bf(float f) {
  u32 u = __float_as_uint(f);
  u += 0x7FFF + ((u >> 16) & 1);   // RNE
  return (u16)(u >> 16);
}

// exp2 via the compiler-visible intrinsic (single v_exp_f32 WITH hazard padding).
__device__ __forceinline__ float vexp2(float x) {
#if __has_builtin(__builtin_amdgcn_exp2f)
  return __builtin_amdgcn_exp2f(x);
#else
  return __expf(x * 0.69314718055994531f);
#endif
}

// async global->LDS, 16B per lane. LDS dst = wave-uniform base + lane*16.
__device__ __forceinline__ void async16(const u16* g, u16* l) {
  __builtin_amdgcn_global_load_lds(
      (const __attribute__((address_space(1))) unsigned int*)g,
      (__attribute__((address_space(3))) unsigned int*)l, 16, 0, 0);
}

// ---------------------------------------------------------------- cast fp32 -> bf16
__global__ void cast_all(const float* __restrict__ x, const float* __restrict__ wq,
                         const float* __restrict__ wp, u16* __restrict__ xo,
                         u16* __restrict__ wqo, u16* __restrict__ wpo) {
  int i = blockIdx.x * 256 + threadIdx.x;        // 2,097,152 threads, 4 floats each
  const float4* src; u16* dst; int off;
  if (i < 1048576)      { src = (const float4*)x;  dst = xo;  off = i; }
  else if (i < 1835008) { src = (const float4*)wq; dst = wqo; off = i - 1048576; }
  else                  { src = (const float4*)wp; dst = wpo; off = i - 1835008; }
  float4 f = src[off];
  ushort4 o;
  o.x = f2bf(f.x); o.y = f2bf(f.y); o.z = f2bf(f.z); o.w = f2bf(f.w);
  ((ushort4*)dst)[off] = o;
}

// ---------------------------------------------------------------- GEMM  C = A * B^T
// Structure frozen at round-4 2-deep prefetch (14-run ledger: all sync-structure
// variants within env+noise floor). Q-columns (n<1024) pre-scaled by log2(e)/8
// (R11/R12, attn 47.3->44.0 combined with symmetric epilogue).
// Round-13: gemm2 (FINAL) retiled BM 64->128, BN 128->64. Same 512-block grid
// (32x16) and 2 blocks/CU, but MFMA:ds_read per K-step goes 8:8 -> 8:6 and the
// B-tile staging per block halves. Non-FINAL path compiles byte-identical
// (IT=4, JT=4 reproduce the old constants). LDS FINAL: 24 KB.
template <bool FINAL>
__global__ __launch_bounds__(256, 3) void gemm_bt(
    const u16* __restrict__ A, const u16* __restrict__ Bw, u16* __restrict__ qkv,
    u16* __restrict__ vt, const float* __restrict__ bias, float* __restrict__ outp) {
  constexpr int K = 1024;
  constexpr int BM = 128;
  constexpr int BN = FINAL ? 64 : 128;
  constexpr int MT = 32;                      // M/BM = 4096/128
  constexpr int IT = 4;                       // 16-row i-tiles per wave (wm covers 64 rows)
  constexpr int JT = FINAL ? 2 : 4;           // 16-col j-frags per wave (wn covers JT*16)
  constexpr int ACALLS = BM / 16;             // wave-calls to stage A tile (1 KB each)
  constexpr int BCALLS = BN / 16;
  constexpr int TCALLS = ACALLS + BCALLS;     // 12 (FINAL) / 16
  constexpr int PW = TCALLS / 4;              // calls per wave: 3 / 4
  const float QS = 0.18033688011112042f;      // log2(e)/8
  const int bm = blockIdx.x % MT;
  const int bn = blockIdx.x / MT;
  const int tid = threadIdx.x;
  const int wave = tid >> 6, lane = tid & 63;
  const int q4 = lane >> 4, l15 = lane & 15;
  const int wm = wave >> 1, wn = wave & 1;
  const int m0 = bm * BM, n0 = bn * BN;

  __shared__ alignas(16) u16 lsA[2][BM * 32];
  __shared__ alignas(16) u16 lsB[2][BN * 32];

  f32x4 acc[IT][JT];
#pragma unroll
  for (int i = 0; i < IT; i++)
#pragma unroll
    for (int j = 0; j < JT; j++) acc[i][j] = (f32x4){0.f, 0.f, 0.f, 0.f};

  auto stage = [&](int k0, int buf) {
#pragma unroll
    for (int j = 0; j < PW; ++j) {
      int t = wave * PW + j;
      if (t < ACALLS) {
        int lin = t * 64 + lane;
        int r = lin >> 2, c = lin & 3;         // 4 x 16B chunks per 32-elem row
        async16(A + (size_t)(m0 + r) * K + k0 + c * 8, lsA[buf] + t * 512);
      } else {
        int tb = t - ACALLS;
        int lin = tb * 64 + lane;
        int r = lin >> 2, c = lin & 3;
        async16(Bw + (size_t)(n0 + r) * K + k0 + c * 8, lsB[buf] + tb * 512);
      }
    }
  };

  stage(0, 0);

  for (int k0 = 0; k0 < K; k0 += 32) {
    const int buf = (k0 >> 5) & 1;
    __syncthreads();                           // stage(k0) landed; prev compute done
    if (k0 + 32 < K) stage(k0 + 32, buf ^ 1);  // prefetch next into other buffer
    s16x8 af[IT], bfr[JT];
#pragma unroll
    for (int i = 0; i < IT; ++i)
      af[i] = *(const s16x8*)(lsA[buf] + (wm * (IT * 16) + i * 16 + l15) * 32 + q4 * 8);
#pragma unroll
    for (int j = 0; j < JT; ++j)
      bfr[j] = *(const s16x8*)(lsB[buf] + (wn * (JT * 16) + j * 16 + l15) * 32 + q4 * 8);
    __builtin_amdgcn_s_setprio(1);
#pragma unroll
    for (int i = 0; i < IT; ++i)
#pragma unroll
      for (int j = 0; j < JT; ++j)
        acc[i][j] = __builtin_amdgcn_mfma_f32_16x16x32_bf16(af[i], bfr[j], acc[i][j], 0, 0, 0);
    __builtin_amdgcn_s_setprio(0);
  }

  // epilogue: C/D layout col=lane&15, row=quad*4+reg
#pragma unroll
  for (int i = 0; i < IT; i++) {
#pragma unroll
    for (int j = 0; j < JT; j++) {
      int n = n0 + wn * (JT * 16) + j * 16 + l15;
      int mb = m0 + wm * (IT * 16) + i * 16 + q4 * 4;
      if (FINAL) {
#pragma unroll
        for (int r = 0; r < 4; r++)
          outp[(size_t)(mb + r) * DIM + n] = acc[i][j][r] + bias[n];
      } else if (n < 2048) {
        float sc = (n < 1024) ? QS : 1.0f;     // pre-scale Q columns for attn
#pragma unroll
        for (int r = 0; r < 4; r++)
          qkv[(size_t)(mb + r) * QKVN + n] = f2bf(acc[i][j][r] * sc);
      } else {
        int b = mb >> 11, tok = mb & 2047;
        int h = (n >> 6) & 15, hd = n & 63;
        ushort4 pk;
        pk.x = f2bf(acc[i][j][0]); pk.y = f2bf(acc[i][j][1]);
        pk.z = f2bf(acc[i][j][2]); pk.w = f2bf(acc[i][j][3]);
        *(ushort4*)(vt + ((size_t)((b * NHEADS + h) * HD + hd)) * NSEQ + tok) = pk;
      }
    }
  }
}

// ---------------------------------------------------------------- flash attention
// BYTE-FROZEN at round-12 (best measured: 43.7-44.3us env A). Contains every
// verified mechanism: x32-permuted PV (R8), matrix-pipe osum + setprio (R10),
// pre-scaled-Q raw prologue + symmetric literal-index epilogue (R11/R12).
// Established dead levers (do not revisit): extra TLP (R9: 4 waves/SIMD
// neutral — kernel is issue-bound at ~73% combined pipes); bank conflicts
// (counter is bit-constant 2162688 across all read variants — staging-side,
// invariant); reg caps below live set (R1/R3 spills); smaller Q/key tiles
// (R2/R3); runtime ext_vector indexing (R11: acc demoted to scratch, 554MB).
__global__ __launch_bounds__(256, 2) void attn_kernel(const u16* __restrict__ qkv,
                                                      const u16* __restrict__ vt,
                                                      u16* __restrict__ aout) {
  const int blk = blockIdx.x;            // 512 = 16 qtiles * 32 bh (bh fast)
  const int bh = blk & 31, qt = blk >> 5;
  const int b = bh >> 4, h = bh & 15;
  const int tid = threadIdx.x;
  const int wave = tid >> 6, lane = tid & 63;
  const int g = wave >> 1, wq = wave & 1;      // key-group, q-position
  const int q4 = lane >> 4, l15 = lane & 15;

  __shared__ alignas(16) u16 smem[32768];      // 64 KB, hand-partitioned
  u16* lsKb = smem + g * 2 * 4096;             // this group's two K buffers
  u16* lsVb = smem + 16384 + g * 2 * 4096;     // this group's two V buffers

  // Q frags (B-operand of S^T MFMA) — pre-scaled by log2(e)/8 in gemm1
  s16x8 aq[4][2];
#pragma unroll
  for (int rt = 0; rt < 4; ++rt)
#pragma unroll
    for (int kc = 0; kc < 2; ++kc) {
      int row = b * NSEQ + qt * 128 + wq * 64 + rt * 16 + l15;
      aq[rt][kc] = *(const s16x8*)(qkv + (size_t)row * QKVN + h * HD + kc * 32 + q4 * 8);
    }

  f32x4 o[4][4];
  f32x4 osum[4];                                   // rowsum(P): row = q4*4+r, dup over l15
  const s16x8 vones8 = {(short)0x3F80, (short)0x3F80, (short)0x3F80, (short)0x3F80,
                        (short)0x3F80, (short)0x3F80, (short)0x3F80, (short)0x3F80};
#pragma unroll
  for (int rt = 0; rt < 4; ++rt) {
    osum[rt] = (f32x4){0.f, 0.f, 0.f, 0.f};
#pragma unroll
    for (int ht = 0; ht < 4; ++ht) o[rt][ht] = (f32x4){0.f, 0.f, 0.f, 0.f};
  }

  // stage tile ktl of this group's key-half into buffer buf (8 K + 8 V calls / 2 waves)
  auto stage = [&](int ktl, int buf) {
#pragma unroll
    for (int j = 0; j < 4; ++j) {
      int t = wq * 4 + j;                          // 0..7
      int lin = t * 64 + lane;
      int r = lin >> 3, c = (lin & 7) ^ (r & 7);
      int key = g * 1024 + ktl * 64;
      async16(qkv + (size_t)(b * NSEQ + key + r) * QKVN + DIM + h * HD + c * 8,
              lsKb + buf * 4096 + t * 512);
      async16(vt + (size_t)(bh * HD + r) * NSEQ + key + c * 8,
              lsVb + buf * 4096 + t * 512);
    }
  };

  stage(0, 0);

  for (int kt = 0; kt < 16; ++kt) {
    const int buf = kt & 1;
    __syncthreads();                               // stage(kt) complete; prev compute done
    if (kt + 1 < 16) stage(kt + 1, buf ^ 1);       // async into other buffer
    const u16* lsK = lsKb + buf * 4096;
    const u16* lsV = lsVb + buf * 4096;

    // hoisted fragment loads (shared by all 4 rt chains)
    s16x8 kf[2][4];                                // [kc][ct]: A-frag K[key][hd]
#pragma unroll
    for (int kc = 0; kc < 2; ++kc)
#pragma unroll
      for (int ct = 0; ct < 4; ++ct) {
        int r = ct * 16 + l15;
        int c = (kc * 4 + q4) ^ (r & 7);
        kf[kc][ct] = *(const s16x8*)(lsK + r * 64 + c * 8);
      }
    // V B-frags in PERMUTED slot order matching pa8 (R8 layout):
    // slot j<4 = keys 32c+4q4+j, slot j>=4 = keys 32c+16+4q4+j-4.
    s16x8 vf8[2][4];                               // [c(32-key chunk)][ht]
#pragma unroll
    for (int c = 0; c < 2; ++c)
#pragma unroll
      for (int ht = 0; ht < 4; ++ht) {
        int row = ht * 16 + l15;                   // hd row in lsV
        int ch0 = c * 4 + (q4 >> 1);               // 16B chunk of keys 32c+4q4..
        int ch1 = ch0 + 2;                         // 16B chunk of keys 32c+16+4q4..
        union { s16x4 hh[2]; s16x8 v; } u;
        u.hh[0] = *(const s16x4*)(lsV + row * 64 + (ch0 ^ (row & 7)) * 8 + (q4 & 1) * 4);
        u.hh[1] = *(const s16x4*)(lsV + row * 64 + (ch1 ^ (row & 7)) * 8 + (q4 & 1) * 4);
        vf8[c][ht] = u.v;
      }

#pragma unroll
    for (int rt = 0; rt < 4; ++rt) {
      // S^T = K * Q^T : per ct, 16 keys x 16 qrows
      f32x4 st[4];
#pragma unroll
      for (int ct = 0; ct < 4; ++ct) st[ct] = (f32x4){0.f, 0.f, 0.f, 0.f};
      __builtin_amdgcn_s_setprio(1);
#pragma unroll
      for (int kc = 0; kc < 2; ++kc)
#pragma unroll
        for (int ct = 0; ct < 4; ++ct)
          st[ct] = __builtin_amdgcn_mfma_f32_16x16x32_bf16(kf[kc][ct], aq[rt][kc], st[ct], 0, 0, 0);
      __builtin_amdgcn_s_setprio(0);

      // P = exp2(S^T), truncated to bf16 in-register, packed directly as the
      // x32 A-frag (w[0..1] = ct=2c, w[2..3] = ct=2c+1)
      s16x8 pa8[2];
#pragma unroll
      for (int c = 0; c < 2; ++c) {
        union { u32 w[4]; s16x8 v; } pk;
#pragma unroll
        for (int h2 = 0; h2 < 2; ++h2) {
          int ct = c * 2 + h2;
          u32 u0 = __float_as_uint(vexp2(st[ct][0]));
          u32 u1 = __float_as_uint(vexp2(st[ct][1]));
          u32 u2 = __float_as_uint(vexp2(st[ct][2]));
          u32 u3 = __float_as_uint(vexp2(st[ct][3]));
          pk.w[h2 * 2 + 0] = (u0 >> 16) | (u1 & 0xffff0000u);
          pk.w[h2 * 2 + 1] = (u2 >> 16) | (u3 & 0xffff0000u);
        }
        pa8[c] = pk.v;
      }

      // O += P * V (16x16x32); rowsum(P) on the matrix pipe (normalizer ==
      // exact MFMA input: same truncated bf16 addends, fp32 accumulation)
      __builtin_amdgcn_s_setprio(1);
#pragma unroll
      for (int c = 0; c < 2; ++c) {
        osum[rt] = __builtin_amdgcn_mfma_f32_16x16x32_bf16(pa8[c], vones8, osum[rt], 0, 0, 0);
#pragma unroll
        for (int ht = 0; ht < 4; ++ht)
          o[rt][ht] = __builtin_amdgcn_mfma_f32_16x16x32_bf16(pa8[c], vf8[c][ht], o[rt][ht], 0, 0, 0);
      }
      __builtin_amdgcn_s_setprio(0);
    }
  }

  // ---- symmetric combine, uniform branches, LITERAL o indices only.
  // Overlay: lsOa (g1's ht{0,1}) 32x132, lsOb (g0's ht{2,3}) 32x132,
  // lsS0 (g0 sums) 128, lsS1 (g1 sums) 128  -> 34,816 B < 64 KB.
  float* lsOa = (float*)smem;
  float* lsOb = lsOa + 32 * 132;
  float* lsS0 = lsOa + 64 * 132;
  float* lsS1 = lsS0 + 128;

  __syncthreads();                                 // all staging reads done; overlay LDS
  if (g == 1) {                                    // publish ht 0,1 + sums
#pragma unroll
    for (int rt = 0; rt < 4; ++rt) {
      int a0 = l15 * 132 + wq * 64 + rt * 16 + q4 * 4;
      *(float4*)(lsOa + a0)            = (float4){o[rt][0][0], o[rt][0][1], o[rt][0][2], o[rt][0][3]};
      *(float4*)(lsOa + a0 + 16 * 132) = (float4){o[rt][1][0], o[rt][1][1], o[rt][1][2], o[rt][1][3]};
      if (l15 == 0) {
#pragma unroll
        for (int r = 0; r < 4; ++r)
          lsS1[wq * 64 + rt * 16 + q4 * 4 + r] = osum[rt][r];
      }
    }
  } else {                                         // publish ht 2,3 + sums
#pragma unroll
    for (int rt = 0; rt < 4; ++rt) {
      int a0 = l15 * 132 + wq * 64 + rt * 16 + q4 * 4;
      *(float4*)(lsOb + a0)            = (float4){o[rt][2][0], o[rt][2][1], o[rt][2][2], o[rt][2][3]};
      *(float4*)(lsOb + a0 + 16 * 132) = (float4){o[rt][3][0], o[rt][3][1], o[rt][3][2], o[rt][3][3]};
      if (l15 == 0) {
#pragma unroll
        for (int r = 0; r < 4; ++r)
          lsS0[wq * 64 + rt * 16 + q4 * 4 + r] = osum[rt][r];
      }
    }
  }
  __syncthreads();
  if (g == 0) {                                    // finish ht 0,1 (cols 0..31)
#pragma unroll
    for (int rt = 0; rt < 4; ++rt) {
      float4 s2 = *(const float4*)(lsS1 + wq * 64 + rt * 16 + q4 * 4);
      float inv[4];
      inv[0] = 1.0f / (osum[rt][0] + s2.x);
      inv[1] = 1.0f / (osum[rt][1] + s2.y);
      inv[2] = 1.0f / (osum[rt][2] + s2.z);
      inv[3] = 1.0f / (osum[rt][3] + s2.w);
      int a0 = l15 * 132 + wq * 64 + rt * 16 + q4 * 4;
      float4 p0 = *(const float4*)(lsOa + a0);
      float4 p1 = *(const float4*)(lsOa + a0 + 16 * 132);
      float v0[4] = {o[rt][0][0] + p0.x, o[rt][0][1] + p0.y, o[rt][0][2] + p0.z, o[rt][0][3] + p0.w};
      float v1[4] = {o[rt][1][0] + p1.x, o[rt][1][1] + p1.y, o[rt][1][2] + p1.z, o[rt][1][3] + p1.w};
#pragma unroll
      for (int r = 0; r < 4; ++r) {
        int n = qt * 128 + wq * 64 + rt * 16 + q4 * 4 + r;
        size_t base = (size_t)(b * NSEQ + n) * DIM + h * HD;
        aout[base + 0  + l15] = f2bf(v0[r] * inv[r]);
        aout[base + 16 + l15] = f2bf(v1[r] * inv[r]);
      }
    }
  } else {                                         // finish ht 2,3 (cols 32..63)
#pragma unroll
    for (int rt = 0; rt < 4; ++rt) {
      float4 s2 = *(const float4*)(lsS0 + wq * 64 + rt * 16 + q4 * 4);
      float inv[4];
      inv[0] = 1.0f / (osum[rt][0] + s2.x);
      inv[1] = 1.0f / (osum[rt][1] + s2.y);
      inv[2] = 1.0f / (osum[rt][2] + s2.z);
      inv[3] = 1.0f / (osum[rt][3] + s2.w);
      int a0 = l15 * 132 + wq * 64 + rt * 16 + q4 * 4;
      float4 p2 = *(const float4*)(lsOb + a0);
      float4 p3 = *(const float4*)(lsOb + a0 + 16 * 132);
      float v2[4] = {o[rt][2][0] + p2.x, o[rt][2][1] + p2.y, o[rt][2][2] + p2.z, o[rt][2][3] + p2.w};
      float v3[4] = {o[rt][3][0] + p3.x, o[rt][3][1] + p3.y, o[rt][3][2] + p3.z, o[rt][3][3] + p3.w};
#pragma unroll
      for (int r = 0; r < 4; ++r) {
        int n = qt * 128 + wq * 64 + rt * 16 + q4 * 4 + r;
        size_t base = (size_t)(b * NSEQ + n) * DIM + h * HD;
        aout[base + 32 + l15] = f2bf(v2[r] * inv[r]);
        aout[base + 48 + l15] = f2bf(v3[r] * inv[r]);
      }
    }
  }
}

// ---------------------------------------------------------------- launch
extern "C" void kernel_launch(void* const* d_in, const int* in_sizes, int n_in,
                              void* d_out, int out_size, void* d_ws, size_t ws_size,
                              hipStream_t stream) {
  const float* x     = (const float*)d_in[0];
  const float* w_qkv = (const float*)d_in[1];
  const float* w_prj = (const float*)d_in[2];
  const float* b_prj = (const float*)d_in[3];
  float* out = (float*)d_out;

  char* ws = (char*)d_ws;
  u16* x_bf    = (u16*)(ws);                          // 8 MB
  u16* wqkv_bf = (u16*)(ws + (size_t)(8u << 20));     // 6 MB
  u16* wprj_bf = (u16*)(ws + (size_t)(14u << 20));    // 2 MB
  u16* qkv     = (u16*)(ws + (size_t)(16u << 20));    // 24 MB (Q,K used; V slot unused)
  u16* vt      = (u16*)(ws + (size_t)(40u << 20));    // 8 MB
  u16* aout    = (u16*)(ws + (size_t)(48u << 20));    // 8 MB   total 56 MB

  cast_all<<<8192, 256, 0, stream>>>(x, w_qkv, w_prj, x_bf, wqkv_bf, wprj_bf);
  gemm_bt<false><<<32 * 24, 256, 0, stream>>>(x_bf, wqkv_bf, qkv, vt, nullptr, nullptr);
  attn_kernel<<<512, 256, 0, stream>>>(qkv, vt, aout);
  gemm_bt<true><<<32 * 16, 256, 0, stream>>>(aout, wprj_bf, nullptr, nullptr, b_prj, out);
}